// Round 11
// baseline (282.446 us; speedup 1.0000x reference)
//
#include <hip/hip_runtime.h>
#include <hip/hip_bf16.h>
#include <stdint.h>

// Problem constants (fixed by the reference)
#define NN    20000      // nodes
#define NP    20096      // nodes padded to 157*128 (garbage rows never read back)
#define EE    320000     // edges (w/o self loops)
#define CH    128        // feature width per gate
#define GC    512        // 4 gates * 128
#define NHtot 2560000    // N*CH

typedef short bf16x8 __attribute__((ext_vector_type(8)));   // 8 bf16 (4 VGPRs)
typedef float f32x4  __attribute__((ext_vector_type(4)));   // 4 fp32 acc

// ---------- bf16 helpers ----------
__device__ __forceinline__ unsigned short f2bf(float f) {
    __hip_bfloat16 b = __float2bfloat16(f);           // RNE
    union { __hip_bfloat16 b; unsigned short u; } c; c.b = b; return c.u;
}
// fast bf16x2 dword -> two f32: lo = u<<16, hi = u & 0xffff0000 (1 VALU op each)
__device__ __forceinline__ void fma4(uint2 u, float n, float* acc) {
    union { unsigned int i; float f; } t;
    t.i = u.x << 16;         acc[0] += n * t.f;
    t.i = u.x & 0xffff0000u; acc[1] += n * t.f;
    t.i = u.y << 16;         acc[2] += n * t.f;
    t.i = u.y & 0xffff0000u; acc[3] += n * t.f;
}
__device__ __forceinline__ void tof4(uint2 u, float* f) {
    union { unsigned int i; float f; } t;
    t.i = u.x << 16;         f[0] = t.f;
    t.i = u.x & 0xffff0000u; f[1] = t.f;
    t.i = u.y << 16;         f[2] = t.f;
    t.i = u.y & 0xffff0000u; f[3] = t.f;
}
__device__ __forceinline__ uint2 pack4(const float* f) {
    uint2 v;
    v.x = (unsigned int)f2bf(f[0]) | ((unsigned int)f2bf(f[1]) << 16);
    v.y = (unsigned int)f2bf(f[2]) | ((unsigned int)f2bf(f[3]) << 16);
    return v;
}

// ---------- 1. MERGED: edge count + weighted degree (atomics) + weight prep + btot ----------
// blocks [0,1250): count+deg; blocks [1250,2274): transpose/cast weights (+btot).
__global__ void k_cntprep(const int* __restrict__ ei, const float* __restrict__ ew,
                          int* __restrict__ cnt, float* __restrict__ deg,
                          const float* __restrict__ W0, const float* __restrict__ W1,
                          const float* __restrict__ W2, const float* __restrict__ W3,
                          unsigned short* __restrict__ T0, unsigned short* __restrict__ T1,
                          unsigned short* __restrict__ T2, unsigned short* __restrict__ T3,
                          const float* __restrict__ bx1, const float* __restrict__ bh1,
                          const float* __restrict__ bg, float* __restrict__ btot) {
    int bid = blockIdx.x;
    if (bid < EE / 256) {
        int e = bid * 256 + threadIdx.x;
        int d = ei[EE + e];
        atomicAdd(&cnt[d], 1);
        atomicAdd(&deg[d], ew[e]);
        return;
    }
    int pid = bid - EE / 256;                        // 0..1023
    int z = pid >> 8, y = (pid >> 6) & 3, xb = pid & 63;
    if (z == 0 && y == 0 && xb < 2) {
        int f = xb * 256 + threadIdx.x;              // 512 entries
        btot[f] = bx1[f] + bh1[f] + bg[f];
    }
    const float* W; unsigned short* T;
    switch (z) {
        case 0:  W = W0; T = T0; break;
        case 1:  W = W1; T = T1; break;
        case 2:  W = W2; T = T2; break;
        default: W = W3; T = T3; break;
    }
    int n = xb * 2 + (threadIdx.x >> 7);
    int k = threadIdx.x & 127;
    T[((size_t)y * 128 + n) * 128 + k] = f2bf(W[((size_t)y * 128 + k) * 128 + n]);
}

// ---------- 2. single-block exclusive scan (1024 thr, 20 elems/thread) ----------
__global__ __launch_bounds__(1024) void k_scanA(const int* __restrict__ cnt,
                                                int* __restrict__ rowoff,
                                                int* __restrict__ cur) {
    __shared__ int wtot[16];
    int t = threadIdx.x;                             // 0..1023
    int base = t * 20;                               // 1024*20 = 20480 >= NN
    int loc[20];
    int s = 0;
    #pragma unroll
    for (int j = 0; j < 20; ++j) {
        int i = base + j;
        int v = (i < NN) ? cnt[i] : 0;
        loc[j] = s; s += v;                          // thread-local exclusive
    }
    int lane = t & 63, wv = t >> 6;
    int ps = s;
    #pragma unroll
    for (int off = 1; off < 64; off <<= 1) {
        int u = __shfl_up(ps, off);
        if (lane >= off) ps += u;
    }
    if (lane == 63) wtot[wv] = ps;
    __syncthreads();
    int wof = 0;
    for (int k = 0; k < wv; ++k) wof += wtot[k];
    int tstart = wof + ps - s;                       // exclusive prefix of thread
    #pragma unroll
    for (int j = 0; j < 20; ++j) {
        int i = base + j;
        if (i < NN) { int v = tstart + loc[j]; rowoff[i] = v; cur[i] = v; }
    }
    if (t == 0) rowoff[NN] = EE;
}

// ---------- 3. MERGED: scatter edges into CSR  ||  dis + scale/pack x|h ----------
// blocks [0,1250): scatter; blocks [1250,6250): degcast (independent work).
__global__ void k_scatdeg(const int* __restrict__ ei, const float* __restrict__ ew,
                          int* __restrict__ cur,
                          int* __restrict__ csrs, float* __restrict__ csrw,
                          const float* __restrict__ deg,
                          const float* __restrict__ x, const float* __restrict__ h,
                          float* __restrict__ dis, unsigned short* __restrict__ xhb) {
    int bid = blockIdx.x;
    if (bid < EE / 256) {
        int e = bid * 256 + threadIdx.x;
        int s = ei[e], d = ei[EE + e];
        int p = atomicAdd(&cur[d], 1);
        csrs[p] = s; csrw[p] = ew[e];
        return;
    }
    int wid = threadIdx.x >> 6, lane = threadIdx.x & 63;
    int w = (bid - EE / 256) * 4 + wid;              // 5000 blocks x 4 nodes = NN
    float dn = rsqrtf(fmaxf(1.0f + deg[w], 1e-12f)); // self-loop weight 1
    if (lane == 0) dis[w] = dn;
    const float* src = (lane < 32) ? x + (size_t)w * CH + lane * 4
                                   : h + (size_t)w * CH + (lane - 32) * 4;
    float4 v = *(const float4*)src;
    float f[4] = { dn * v.x, dn * v.y, dn * v.z, dn * v.w };
    *(uint2*)(xhb + (size_t)w * 256 + lane * 4) = pack4(f);
}

// ---------- 4. fused prop over packed 256-wide bf16 rows (table pre-scaled) ----------
// axh[w] = dis_w*(sum_e w_e*T[s_e] + T[w]); 1 wave/node, 8B/lane, 8-edge unroll.
__global__ __launch_bounds__(128) void k_prop256(
        const unsigned short* __restrict__ tab, unsigned short* __restrict__ o,
        const int* __restrict__ rowoff, const int* __restrict__ csrs,
        const float* __restrict__ csrw, const float* __restrict__ dis) {
    int w = blockIdx.x * 2 + (threadIdx.x >> 6);     // grid exact: NN/2 blocks
    int lane = threadIdx.x & 63;
    const uint2* T2 = (const uint2*)tab;             // row = 64 uint2 = 512 B
    float acc[4];
    tof4(T2[(size_t)w * 64 + lane], acc);            // self term (pre-scaled table)
    int e = rowoff[w], e1 = rowoff[w + 1];
    for (; e + 8 <= e1; e += 8) {                    // 8 gathers in flight
        int   s0 = csrs[e],   s1 = csrs[e+1], s2 = csrs[e+2], s3 = csrs[e+3];
        int   s4 = csrs[e+4], s5 = csrs[e+5], s6 = csrs[e+6], s7 = csrs[e+7];
        uint2 u0 = T2[(size_t)s0 * 64 + lane];
        uint2 u1 = T2[(size_t)s1 * 64 + lane];
        uint2 u2 = T2[(size_t)s2 * 64 + lane];
        uint2 u3 = T2[(size_t)s3 * 64 + lane];
        uint2 u4 = T2[(size_t)s4 * 64 + lane];
        uint2 u5 = T2[(size_t)s5 * 64 + lane];
        uint2 u6 = T2[(size_t)s6 * 64 + lane];
        uint2 u7 = T2[(size_t)s7 * 64 + lane];
        float n0 = csrw[e],   n1 = csrw[e+1], n2 = csrw[e+2], n3 = csrw[e+3];
        float n4 = csrw[e+4], n5 = csrw[e+5], n6 = csrw[e+6], n7 = csrw[e+7];
        fma4(u0, n0, acc); fma4(u1, n1, acc); fma4(u2, n2, acc); fma4(u3, n3, acc);
        fma4(u4, n4, acc); fma4(u5, n5, acc); fma4(u6, n6, acc); fma4(u7, n7, acc);
    }
    for (; e + 4 <= e1; e += 4) {
        int   s0 = csrs[e],   s1 = csrs[e+1], s2 = csrs[e+2], s3 = csrs[e+3];
        float n0 = csrw[e],   n1 = csrw[e+1], n2 = csrw[e+2], n3 = csrw[e+3];
        uint2 u0 = T2[(size_t)s0 * 64 + lane];
        uint2 u1 = T2[(size_t)s1 * 64 + lane];
        uint2 u2 = T2[(size_t)s2 * 64 + lane];
        uint2 u3 = T2[(size_t)s3 * 64 + lane];
        fma4(u0, n0, acc); fma4(u1, n1, acc); fma4(u2, n2, acc); fma4(u3, n3, acc);
    }
    for (; e < e1; ++e) {
        fma4(T2[(size_t)csrs[e] * 64 + lane], csrw[e], acc);
    }
    float dw = dis[w];
    #pragma unroll
    for (int j = 0; j < 4; ++j) acc[j] *= dw;
    ((uint2*)o)[(size_t)w * 64 + lane] = pack4(acc);
}

// ---------- MFMA GEMM shared machinery ----------
#define SWZ(r, c8) (((r) << 4) + ((c8) ^ ((r) & 15)))

// ---------- 5. GEMM1 (both sides in one launch via blockIdx.z) ----------
// h0 = relu(axh[:, side] @ W0[g] + b0[g]) -> bf16 [NP,512]
__global__ __launch_bounds__(256) void k_gemm1(
        const unsigned short* __restrict__ A,
        const unsigned short* __restrict__ Wtx, const unsigned short* __restrict__ Wth,
        const float* __restrict__ bx0, const float* __restrict__ bh0,
        unsigned short* __restrict__ outx, unsigned short* __restrict__ outh) {
    __shared__ uint4 As[2048];                       // 32 KB
    __shared__ uint4 Bs[2048];                       // 32 KB
    const int side = blockIdx.z;
    const int aoff = side * 128;
    const unsigned short* Wt = side ? Wth : Wtx;
    const float* bias        = side ? bh0 : bx0;
    unsigned short* out      = side ? outh : outx;

    const int    g    = blockIdx.y;
    const size_t row0 = (size_t)blockIdx.x * 128;
    const int    t    = threadIdx.x;

    #pragma unroll
    for (int p = 0; p < 8; ++p) {                    // stage A 128x128 bf16
        int id = t + 256 * p, r = id >> 4, c8 = id & 15;
        As[SWZ(r, c8)] = *(const uint4*)(A + (row0 + r) * 256 + aoff + c8 * 8);
    }
    const unsigned short* Wg = Wt + (size_t)g * 16384;   // [n][k] bf16
    #pragma unroll
    for (int p = 0; p < 8; ++p) {                    // stage W^T 128x128 bf16
        int id = t + 256 * p, r = id >> 4, c8 = id & 15;
        Bs[SWZ(r, c8)] = *(const uint4*)(Wg + r * CH + c8 * 8);
    }
    __syncthreads();

    const int wid = t >> 6, l = t & 63;
    const int m0 = (wid >> 1) * 64, n0 = (wid & 1) * 64;
    const int lm = l & 15, q = l >> 4;
    f32x4 acc[4][4];
    #pragma unroll
    for (int i = 0; i < 4; ++i)
        #pragma unroll
        for (int j = 0; j < 4; ++j) { acc[i][j][0]=0.f; acc[i][j][1]=0.f; acc[i][j][2]=0.f; acc[i][j][3]=0.f; }

    #pragma unroll
    for (int kc = 0; kc < 4; ++kc) {
        int c8 = kc * 4 + q;
        bf16x8 a[4], b[4];
        #pragma unroll
        for (int i = 0; i < 4; ++i) { int r = m0 + i * 16 + lm; a[i] = *(const bf16x8*)&As[SWZ(r, c8)]; }
        #pragma unroll
        for (int j = 0; j < 4; ++j) { int r = n0 + j * 16 + lm; b[j] = *(const bf16x8*)&Bs[SWZ(r, c8)]; }
        #pragma unroll
        for (int i = 0; i < 4; ++i)
            #pragma unroll
            for (int j = 0; j < 4; ++j)
                acc[i][j] = __builtin_amdgcn_mfma_f32_16x16x32_bf16(a[i], b[j], acc[i][j], 0, 0, 0);
    }

    #pragma unroll
    for (int j = 0; j < 4; ++j) {
        float bb = bias[g * CH + n0 + j * 16 + lm];
        #pragma unroll
        for (int i = 0; i < 4; ++i)
            #pragma unroll
            for (int r = 0; r < 4; ++r) {
                int rowl = m0 + i * 16 + q * 4 + r;   // C/D: row=(lane>>4)*4+reg
                int col  = n0 + j * 16 + lm;          //      col=lane&15
                out[(row0 + rowl) * GC + g * CH + col] = f2bf(fmaxf(acc[i][j][r] + bb, 0.f));
            }
    }
}

// ---------- 6. GEMM2 (fused): Sb = dis .* (h0x@Wx1 + h0h@Wh1) -> bf16 [NP,512] ----------
__global__ __launch_bounds__(256) void k_gemm2(
        const unsigned short* __restrict__ A1, const unsigned short* __restrict__ A2,
        const unsigned short* __restrict__ Wt1, const unsigned short* __restrict__ Wt2,
        const float* __restrict__ dis, unsigned short* __restrict__ outS) {
    __shared__ uint4 As[2048];
    __shared__ uint4 Bs[2048];
    const int    g    = blockIdx.y;
    const size_t row0 = (size_t)blockIdx.x * 128;
    const int    t    = threadIdx.x;
    const int wid = t >> 6, l = t & 63;
    const int m0 = (wid >> 1) * 64, n0 = (wid & 1) * 64;
    const int lm = l & 15, q = l >> 4;
    f32x4 acc[4][4];
    #pragma unroll
    for (int i = 0; i < 4; ++i)
        #pragma unroll
        for (int j = 0; j < 4; ++j) { acc[i][j][0]=0.f; acc[i][j][1]=0.f; acc[i][j][2]=0.f; acc[i][j][3]=0.f; }

    for (int side = 0; side < 2; ++side) {
        if (side) __syncthreads();                   // all waves done reading LDS
        const unsigned short* Ap = side ? A2 : A1;
        const unsigned short* Wg = (side ? Wt2 : Wt1) + (size_t)g * 16384;
        #pragma unroll
        for (int p = 0; p < 8; ++p) {
            int id = t + 256 * p, r = id >> 4, c8 = id & 15;
            As[SWZ(r, c8)] = *(const uint4*)(Ap + (row0 + r) * GC + g * CH + c8 * 8);
        }
        #pragma unroll
        for (int p = 0; p < 8; ++p) {
            int id = t + 256 * p, r = id >> 4, c8 = id & 15;
            Bs[SWZ(r, c8)] = *(const uint4*)(Wg + r * CH + c8 * 8);
        }
        __syncthreads();
        #pragma unroll
        for (int kc = 0; kc < 4; ++kc) {
            int c8 = kc * 4 + q;
            bf16x8 a[4], b[4];
            #pragma unroll
            for (int i = 0; i < 4; ++i) { int r = m0 + i * 16 + lm; a[i] = *(const bf16x8*)&As[SWZ(r, c8)]; }
            #pragma unroll
            for (int j = 0; j < 4; ++j) { int r = n0 + j * 16 + lm; b[j] = *(const bf16x8*)&Bs[SWZ(r, c8)]; }
            #pragma unroll
            for (int i = 0; i < 4; ++i)
                #pragma unroll
                for (int j = 0; j < 4; ++j)
                    acc[i][j] = __builtin_amdgcn_mfma_f32_16x16x32_bf16(a[i], b[j], acc[i][j], 0, 0, 0);
        }
    }

    #pragma unroll
    for (int j = 0; j < 4; ++j)
        #pragma unroll
        for (int i = 0; i < 4; ++i)
            #pragma unroll
            for (int r = 0; r < 4; ++r) {
                int rowl = m0 + i * 16 + q * 4 + r;
                int col  = n0 + j * 16 + lm;
                float dr = dis[row0 + rowl];         // pre-scale for prop512g
                outS[(row0 + rowl) * GC + g * CH + col] = f2bf(dr * acc[i][j][r]);
            }
}

// ---------- 7. prop over 512-wide pre-scaled bf16 + FUSED LSTM gates ----------
// ONE NODE per 128-thread block: 2 waves each gather half the features (8B/lane),
// 8-edge unroll (uint2 keeps VGPR low -> occupancy stays high).
#define GIDX(f) ((f) + ((f) >> 5))                  // +1 float pad per 32 -> conflict-free
__global__ __launch_bounds__(128) void k_prop512g(
        const unsigned short* __restrict__ Sb, float* __restrict__ out,
        const int* __restrict__ rowoff, const int* __restrict__ csrs,
        const float* __restrict__ csrw, const float* __restrict__ dis,
        const float* __restrict__ c, const float* __restrict__ btot,
        const float* __restrict__ wc) {
    __shared__ float gbuf[528];                      // 2.1 KB
    int half = threadIdx.x >> 6, lane = threadIdx.x & 63;
    int w = blockIdx.x;                              // grid exact: NN blocks
    const uint2* S2 = (const uint2*)Sb;              // row = 128 uint2 = 1 KB
    size_t foff = (size_t)half * 64 + lane;          // uint2 offset within row
    float acc[4];
    tof4(S2[(size_t)w * 128 + foff], acc);           // self term (pre-scaled table)
    int e = rowoff[w], e1 = rowoff[w + 1];
    for (; e + 8 <= e1; e += 8) {                    // 8 gathers in flight
        int   s0 = csrs[e],   s1 = csrs[e+1], s2 = csrs[e+2], s3 = csrs[e+3];
        int   s4 = csrs[e+4], s5 = csrs[e+5], s6 = csrs[e+6], s7 = csrs[e+7];
        uint2 u0 = S2[(size_t)s0 * 128 + foff];
        uint2 u1 = S2[(size_t)s1 * 128 + foff];
        uint2 u2 = S2[(size_t)s2 * 128 + foff];
        uint2 u3 = S2[(size_t)s3 * 128 + foff];
        uint2 u4 = S2[(size_t)s4 * 128 + foff];
        uint2 u5 = S2[(size_t)s5 * 128 + foff];
        uint2 u6 = S2[(size_t)s6 * 128 + foff];
        uint2 u7 = S2[(size_t)s7 * 128 + foff];
        float n0 = csrw[e],   n1 = csrw[e+1], n2 = csrw[e+2], n3 = csrw[e+3];
        float n4 = csrw[e+4], n5 = csrw[e+5], n6 = csrw[e+6], n7 = csrw[e+7];
        fma4(u0, n0, acc); fma4(u1, n1, acc); fma4(u2, n2, acc); fma4(u3, n3, acc);
        fma4(u4, n4, acc); fma4(u5, n5, acc); fma4(u6, n6, acc); fma4(u7, n7, acc);
    }
    for (; e + 4 <= e1; e += 4) {
        int   s0 = csrs[e],   s1 = csrs[e+1], s2 = csrs[e+2], s3 = csrs[e+3];
        float n0 = csrw[e],   n1 = csrw[e+1], n2 = csrw[e+2], n3 = csrw[e+3];
        uint2 u0 = S2[(size_t)s0 * 128 + foff];
        uint2 u1 = S2[(size_t)s1 * 128 + foff];
        uint2 u2 = S2[(size_t)s2 * 128 + foff];
        uint2 u3 = S2[(size_t)s3 * 128 + foff];
        fma4(u0, n0, acc); fma4(u1, n1, acc); fma4(u2, n2, acc); fma4(u3, n3, acc);
    }
    for (; e < e1; ++e) {
        fma4(S2[(size_t)csrs[e] * 128 + foff], csrw[e], acc);
    }
    float dw = dis[w];
    #pragma unroll
    for (int j = 0; j < 4; ++j) {
        int f = half * 256 + lane * 4 + j;
        gbuf[GIDX(f)] = dw * acc[j];                 // G (pre-bias) into LDS
    }
    __syncthreads();
    int hh = threadIdx.x;                            // 0..127
    float g0 = gbuf[GIDX(hh)]       + btot[hh];
    float g1 = gbuf[GIDX(128 + hh)] + btot[128 + hh];
    float g2 = gbuf[GIDX(256 + hh)] + btot[256 + hh];
    float g3 = gbuf[GIDX(384 + hh)] + btot[384 + hh];
    float cv = c[(size_t)w * CH + hh];
    float I  = 1.f / (1.f + expf(-(g0 + wc[hh]       * cv)));
    float F  = 1.f / (1.f + expf(-(g1 + wc[128 + hh] * cv)));
    float T  = tanhf(g2);
    float Cn = F * cv + I * T;
    float O  = 1.f / (1.f + expf(-(g3 + wc[256 + hh] * Cn)));
    out[(size_t)w * CH + hh]         = O * tanhf(Cn);   // Hn
    out[NHtot + (size_t)w * CH + hh] = Cn;              // Cn
}

extern "C" void kernel_launch(void* const* d_in, const int* in_sizes, int n_in,
                              void* d_out, int out_size, void* d_ws, size_t ws_size,
                              hipStream_t stream) {
    (void)in_sizes; (void)n_in; (void)out_size; (void)ws_size;
    const float* x   = (const float*)d_in[0];
    const int*   ei  = (const int*)d_in[1];
    const float* ew  = (const float*)d_in[2];
    const float* h   = (const float*)d_in[3];
    const float* c   = (const float*)d_in[4];
    const float* Wx0 = (const float*)d_in[5];
    const float* bx0 = (const float*)d_in[6];
    const float* Wx1 = (const float*)d_in[7];
    const float* bx1 = (const float*)d_in[8];
    const float* Wh0 = (const float*)d_in[9];
    const float* bh0 = (const float*)d_in[10];
    const float* Wh1 = (const float*)d_in[11];
    const float* bh1 = (const float*)d_in[12];
    const float* wc  = (const float*)d_in[13];
    const float* bg  = (const float*)d_in[14];
    float* out = (float*)d_out;

    // Workspace layout (float units). cnt+deg contiguous for a single memset.
    float* wsf  = (float*)d_ws;
    float* dis  = wsf;                                  // [20480]
    int*   cnt  = (int*)(wsf + 20480);                  // [20480]  zeroed
    float* deg  = wsf + 40960;                          // [20480]  zeroed
    int*   row  = (int*)(wsf + 61440);                  // [20736]
    int*   cur  = (int*)(wsf + 82176);                  // [20480]
    float* btot = wsf + 102656;                         // [512]
    int*   csrs = (int*)(wsf + 103168);                 // [E]
    float* csrw = wsf + 423168;                         // [E]
    unsigned short* Wt0x = (unsigned short*)(wsf + 743168);   // +32768 floats each
    unsigned short* Wt0h = (unsigned short*)(wsf + 775936);
    unsigned short* Wt1x = (unsigned short*)(wsf + 808704);
    unsigned short* Wt1h = (unsigned short*)(wsf + 841472);
    unsigned short* xhb  = (unsigned short*)(wsf + 874240);   // [NP*256] bf16
    unsigned short* axh  = (unsigned short*)(wsf + 3446528);  // [NP*256] bf16
    unsigned short* h0x  = (unsigned short*)(wsf + 6018816);  // [NP*512] bf16
    unsigned short* h0h  = (unsigned short*)(wsf + 11163392); // [NP*512] bf16
    unsigned short* Sb   = (unsigned short*)(wsf + 16307968); // [NP*512] bf16

    hipMemsetAsync(cnt, 0, 2 * 20480 * sizeof(float), stream);   // cnt + deg

    k_cntprep<<<EE / 256 + 1024, 256, 0, stream>>>(ei, ew, cnt, deg,
                                                   Wx0, Wh0, Wx1, Wh1,
                                                   Wt0x, Wt0h, Wt1x, Wt1h,
                                                   bx1, bh1, bg, btot);
    k_scanA  <<<1, 1024, 0, stream>>>(cnt, row, cur);
    k_scatdeg<<<EE / 256 + NN / 4, 256, 0, stream>>>(ei, ew, cur, csrs, csrw,
                                                     deg, x, h, dis, xhb);

    k_prop256<<<NN / 2, 128, 0, stream>>>(xhb, axh, row, csrs, csrw, dis);

    dim3 g1(NP / 128, 4, 2);
    k_gemm1<<<g1, 256, 0, stream>>>(axh, Wt0x, Wt0h, bx0, bh0, h0x, h0h);
    dim3 g2(NP / 128, 4);
    k_gemm2<<<g2, 256, 0, stream>>>(h0x, h0h, Wt1x, Wt1h, dis, Sb);

    k_prop512g<<<NN, 128, 0, stream>>>(Sb, out, row, csrs, csrw, dis, c, btot, wc);
}

// Round 12
// 253.150 us; speedup vs baseline: 1.1157x; 1.1157x over previous
//
#include <hip/hip_runtime.h>
#include <hip/hip_bf16.h>
#include <stdint.h>

// Problem constants (fixed by the reference)
#define NN    20000      // nodes
#define NP    20096      // nodes padded to 157*128 (garbage rows never read back)
#define EE    320000     // edges (w/o self loops)
#define CH    128        // feature width per gate
#define GC    512        // 4 gates * 128
#define NHtot 2560000    // N*CH

typedef short bf16x8 __attribute__((ext_vector_type(8)));   // 8 bf16 (4 VGPRs)
typedef float f32x4  __attribute__((ext_vector_type(4)));   // 4 fp32 acc

// ---------- bf16 helpers ----------
__device__ __forceinline__ unsigned short f2bf(float f) {
    __hip_bfloat16 b = __float2bfloat16(f);           // RNE
    union { __hip_bfloat16 b; unsigned short u; } c; c.b = b; return c.u;
}
// fast bf16x2 dword -> two f32: lo = u<<16, hi = u & 0xffff0000 (1 VALU op each)
__device__ __forceinline__ void fma4(uint2 u, float n, float* acc) {
    union { unsigned int i; float f; } t;
    t.i = u.x << 16;         acc[0] += n * t.f;
    t.i = u.x & 0xffff0000u; acc[1] += n * t.f;
    t.i = u.y << 16;         acc[2] += n * t.f;
    t.i = u.y & 0xffff0000u; acc[3] += n * t.f;
}
__device__ __forceinline__ void tof4(uint2 u, float* f) {
    union { unsigned int i; float f; } t;
    t.i = u.x << 16;         f[0] = t.f;
    t.i = u.x & 0xffff0000u; f[1] = t.f;
    t.i = u.y << 16;         f[2] = t.f;
    t.i = u.y & 0xffff0000u; f[3] = t.f;
}
__device__ __forceinline__ uint2 pack4(const float* f) {
    uint2 v;
    v.x = (unsigned int)f2bf(f[0]) | ((unsigned int)f2bf(f[1]) << 16);
    v.y = (unsigned int)f2bf(f[2]) | ((unsigned int)f2bf(f[3]) << 16);
    return v;
}

// ---------- 1. MERGED: edge count (int atomics) + weight prep + btot ----------
// blocks [0,1250): count; blocks [1250,2274): transpose/cast weights (+btot).
__global__ void k_cntprep(const int* __restrict__ ei, int* __restrict__ cnt,
                          const float* __restrict__ W0, const float* __restrict__ W1,
                          const float* __restrict__ W2, const float* __restrict__ W3,
                          unsigned short* __restrict__ T0, unsigned short* __restrict__ T1,
                          unsigned short* __restrict__ T2, unsigned short* __restrict__ T3,
                          const float* __restrict__ bx1, const float* __restrict__ bh1,
                          const float* __restrict__ bg, float* __restrict__ btot) {
    int bid = blockIdx.x;
    if (bid < EE / 256) {
        int e = bid * 256 + threadIdx.x;
        atomicAdd(&cnt[ei[EE + e]], 1);
        return;
    }
    int pid = bid - EE / 256;                        // 0..1023
    int z = pid >> 8, y = (pid >> 6) & 3, xb = pid & 63;
    if (z == 0 && y == 0 && xb < 2) {
        int f = xb * 256 + threadIdx.x;              // 512 entries
        btot[f] = bx1[f] + bh1[f] + bg[f];
    }
    const float* W; unsigned short* T;
    switch (z) {
        case 0:  W = W0; T = T0; break;
        case 1:  W = W1; T = T1; break;
        case 2:  W = W2; T = T2; break;
        default: W = W3; T = T3; break;
    }
    int n = xb * 2 + (threadIdx.x >> 7);
    int k = threadIdx.x & 127;
    T[((size_t)y * 128 + n) * 128 + k] = f2bf(W[((size_t)y * 128 + k) * 128 + n]);
}

// ---------- 2. hierarchical exclusive scan of counts ----------
__global__ void k_scan1(const int* __restrict__ cnt, int* __restrict__ rowoff,
                        int* __restrict__ bsum) {
    __shared__ int wsum[4];
    int i = blockIdx.x * 256 + threadIdx.x;
    int self = (i < NN) ? cnt[i] : 0;
    int lane = threadIdx.x & 63, wid = threadIdx.x >> 6;
    int v = self;
    #pragma unroll
    for (int off = 1; off < 64; off <<= 1) {
        int u = __shfl_up(v, off);
        if (lane >= off) v += u;
    }
    if (lane == 63) wsum[wid] = v;
    __syncthreads();
    int wof = 0;
    for (int k = 0; k < wid; ++k) wof += wsum[k];
    if (i < NN) rowoff[i] = wof + v - self;
    if (threadIdx.x == 255) bsum[blockIdx.x] = wof + v;
}

__global__ void k_scan2(int* __restrict__ bsum) {
    int lane = threadIdx.x;                          // 64 threads
    int base = 0;
    for (int start = 0; start < 80; start += 64) {
        int i = start + lane;
        int self = (i < 80) ? bsum[i] : 0;
        int v = self;
        #pragma unroll
        for (int off = 1; off < 64; off <<= 1) {
            int u = __shfl_up(v, off);
            if (lane >= off) v += u;
        }
        if (i < 80) bsum[i] = base + v - self;
        base += __shfl(v, 63);
    }
}

__global__ void k_scan3(int* __restrict__ rowoff, const int* __restrict__ bsum,
                        int* __restrict__ cur) {
    int i = blockIdx.x * 256 + threadIdx.x;
    if (i < NN) {
        int v = rowoff[i] + bsum[i >> 8];
        rowoff[i] = v; cur[i] = v;
    }
    if (i == NN) rowoff[NN] = EE;
}

// ---------- 3. scatter edges into CSR with RAW weights ----------
__global__ void k_scatter(const int* __restrict__ ei, const float* __restrict__ ew,
                          int* __restrict__ cur,
                          int* __restrict__ csrs, float* __restrict__ csrw) {
    int e = blockIdx.x * 256 + threadIdx.x;
    if (e >= EE) return;
    int s = ei[e], d = ei[EE + e];
    int p = atomicAdd(&cur[d], 1);
    csrs[p] = s; csrw[p] = ew[e];
}

// ---------- 4. FUSED: degree row-sum -> dis -> scale & pack x|h to bf16 ----------
__global__ __launch_bounds__(256) void k_degcast(
        const float* __restrict__ x, const float* __restrict__ h,
        const int* __restrict__ rowoff, const float* __restrict__ csrw,
        float* __restrict__ dis, unsigned short* __restrict__ xhb) {
    int wid = threadIdx.x >> 6, lane = threadIdx.x & 63;
    int w = blockIdx.x * 4 + wid;                    // grid exact: NN/4
    int e0 = rowoff[w], e1 = rowoff[w + 1];
    float s = 0.f;
    for (int e = e0 + lane; e < e1; e += 64) s += csrw[e];
    #pragma unroll
    for (int off = 32; off; off >>= 1) s += __shfl_xor(s, off);
    float dn = rsqrtf(fmaxf(1.0f + s, 1e-12f));      // self-loop weight 1
    if (lane == 0) dis[w] = dn;
    const float* src = (lane < 32) ? x + (size_t)w * CH + lane * 4
                                   : h + (size_t)w * CH + (lane - 32) * 4;
    float4 v = *(const float4*)src;
    float f[4] = { dn * v.x, dn * v.y, dn * v.z, dn * v.w };
    *(uint2*)(xhb + (size_t)w * 256 + lane * 4) = pack4(f);
}

// ---------- 5. fused prop over packed 256-wide bf16 rows (table pre-scaled) ----------
// axh[w] = dis_w*(sum_e w_e*T[s_e] + T[w]); 1 wave/node, 8B/lane, 8-edge unroll.
__global__ __launch_bounds__(128) void k_prop256(
        const unsigned short* __restrict__ tab, unsigned short* __restrict__ o,
        const int* __restrict__ rowoff, const int* __restrict__ csrs,
        const float* __restrict__ csrw, const float* __restrict__ dis) {
    int w = blockIdx.x * 2 + (threadIdx.x >> 6);     // grid exact: NN/2 blocks
    int lane = threadIdx.x & 63;
    const uint2* T2 = (const uint2*)tab;             // row = 64 uint2 = 512 B
    float acc[4];
    tof4(T2[(size_t)w * 64 + lane], acc);            // self term (pre-scaled table)
    int e = rowoff[w], e1 = rowoff[w + 1];
    for (; e + 8 <= e1; e += 8) {                    // 8 gathers in flight
        int   s0 = csrs[e],   s1 = csrs[e+1], s2 = csrs[e+2], s3 = csrs[e+3];
        int   s4 = csrs[e+4], s5 = csrs[e+5], s6 = csrs[e+6], s7 = csrs[e+7];
        uint2 u0 = T2[(size_t)s0 * 64 + lane];
        uint2 u1 = T2[(size_t)s1 * 64 + lane];
        uint2 u2 = T2[(size_t)s2 * 64 + lane];
        uint2 u3 = T2[(size_t)s3 * 64 + lane];
        uint2 u4 = T2[(size_t)s4 * 64 + lane];
        uint2 u5 = T2[(size_t)s5 * 64 + lane];
        uint2 u6 = T2[(size_t)s6 * 64 + lane];
        uint2 u7 = T2[(size_t)s7 * 64 + lane];
        float n0 = csrw[e],   n1 = csrw[e+1], n2 = csrw[e+2], n3 = csrw[e+3];
        float n4 = csrw[e+4], n5 = csrw[e+5], n6 = csrw[e+6], n7 = csrw[e+7];
        fma4(u0, n0, acc); fma4(u1, n1, acc); fma4(u2, n2, acc); fma4(u3, n3, acc);
        fma4(u4, n4, acc); fma4(u5, n5, acc); fma4(u6, n6, acc); fma4(u7, n7, acc);
    }
    for (; e + 4 <= e1; e += 4) {
        int   s0 = csrs[e],   s1 = csrs[e+1], s2 = csrs[e+2], s3 = csrs[e+3];
        float n0 = csrw[e],   n1 = csrw[e+1], n2 = csrw[e+2], n3 = csrw[e+3];
        uint2 u0 = T2[(size_t)s0 * 64 + lane];
        uint2 u1 = T2[(size_t)s1 * 64 + lane];
        uint2 u2 = T2[(size_t)s2 * 64 + lane];
        uint2 u3 = T2[(size_t)s3 * 64 + lane];
        fma4(u0, n0, acc); fma4(u1, n1, acc); fma4(u2, n2, acc); fma4(u3, n3, acc);
    }
    for (; e < e1; ++e) {
        fma4(T2[(size_t)csrs[e] * 64 + lane], csrw[e], acc);
    }
    float dw = dis[w];
    #pragma unroll
    for (int j = 0; j < 4; ++j) acc[j] *= dw;
    ((uint2*)o)[(size_t)w * 64 + lane] = pack4(acc);
}

// ---------- MFMA GEMM shared machinery ----------
#define SWZ(r, c8) (((r) << 4) + ((c8) ^ ((r) & 15)))

// ---------- 6. GEMM1 (both sides in one launch via blockIdx.z) ----------
// h0 = relu(axh[:, side] @ W0[g] + b0[g]) -> bf16 [NP,512]
__global__ __launch_bounds__(256) void k_gemm1(
        const unsigned short* __restrict__ A,
        const unsigned short* __restrict__ Wtx, const unsigned short* __restrict__ Wth,
        const float* __restrict__ bx0, const float* __restrict__ bh0,
        unsigned short* __restrict__ outx, unsigned short* __restrict__ outh) {
    __shared__ uint4 As[2048];                       // 32 KB
    __shared__ uint4 Bs[2048];                       // 32 KB
    const int side = blockIdx.z;
    const int aoff = side * 128;
    const unsigned short* Wt = side ? Wth : Wtx;
    const float* bias        = side ? bh0 : bx0;
    unsigned short* out      = side ? outh : outx;

    const int    g    = blockIdx.y;
    const size_t row0 = (size_t)blockIdx.x * 128;
    const int    t    = threadIdx.x;

    #pragma unroll
    for (int p = 0; p < 8; ++p) {                    // stage A 128x128 bf16
        int id = t + 256 * p, r = id >> 4, c8 = id & 15;
        As[SWZ(r, c8)] = *(const uint4*)(A + (row0 + r) * 256 + aoff + c8 * 8);
    }
    const unsigned short* Wg = Wt + (size_t)g * 16384;   // [n][k] bf16
    #pragma unroll
    for (int p = 0; p < 8; ++p) {                    // stage W^T 128x128 bf16
        int id = t + 256 * p, r = id >> 4, c8 = id & 15;
        Bs[SWZ(r, c8)] = *(const uint4*)(Wg + r * CH + c8 * 8);
    }
    __syncthreads();

    const int wid = t >> 6, l = t & 63;
    const int m0 = (wid >> 1) * 64, n0 = (wid & 1) * 64;
    const int lm = l & 15, q = l >> 4;
    f32x4 acc[4][4];
    #pragma unroll
    for (int i = 0; i < 4; ++i)
        #pragma unroll
        for (int j = 0; j < 4; ++j) { acc[i][j][0]=0.f; acc[i][j][1]=0.f; acc[i][j][2]=0.f; acc[i][j][3]=0.f; }

    #pragma unroll
    for (int kc = 0; kc < 4; ++kc) {
        int c8 = kc * 4 + q;
        bf16x8 a[4], b[4];
        #pragma unroll
        for (int i = 0; i < 4; ++i) { int r = m0 + i * 16 + lm; a[i] = *(const bf16x8*)&As[SWZ(r, c8)]; }
        #pragma unroll
        for (int j = 0; j < 4; ++j) { int r = n0 + j * 16 + lm; b[j] = *(const bf16x8*)&Bs[SWZ(r, c8)]; }
        #pragma unroll
        for (int i = 0; i < 4; ++i)
            #pragma unroll
            for (int j = 0; j < 4; ++j)
                acc[i][j] = __builtin_amdgcn_mfma_f32_16x16x32_bf16(a[i], b[j], acc[i][j], 0, 0, 0);
    }

    #pragma unroll
    for (int j = 0; j < 4; ++j) {
        float bb = bias[g * CH + n0 + j * 16 + lm];
        #pragma unroll
        for (int i = 0; i < 4; ++i)
            #pragma unroll
            for (int r = 0; r < 4; ++r) {
                int rowl = m0 + i * 16 + q * 4 + r;   // C/D: row=(lane>>4)*4+reg
                int col  = n0 + j * 16 + lm;          //      col=lane&15
                out[(row0 + rowl) * GC + g * CH + col] = f2bf(fmaxf(acc[i][j][r] + bb, 0.f));
            }
    }
}

// ---------- 7. GEMM2 (fused): Sb = dis .* (h0x@Wx1 + h0h@Wh1) -> bf16 [NP,512] ----------
__global__ __launch_bounds__(256) void k_gemm2(
        const unsigned short* __restrict__ A1, const unsigned short* __restrict__ A2,
        const unsigned short* __restrict__ Wt1, const unsigned short* __restrict__ Wt2,
        const float* __restrict__ dis, unsigned short* __restrict__ outS) {
    __shared__ uint4 As[2048];
    __shared__ uint4 Bs[2048];
    const int    g    = blockIdx.y;
    const size_t row0 = (size_t)blockIdx.x * 128;
    const int    t    = threadIdx.x;
    const int wid = t >> 6, l = t & 63;
    const int m0 = (wid >> 1) * 64, n0 = (wid & 1) * 64;
    const int lm = l & 15, q = l >> 4;
    f32x4 acc[4][4];
    #pragma unroll
    for (int i = 0; i < 4; ++i)
        #pragma unroll
        for (int j = 0; j < 4; ++j) { acc[i][j][0]=0.f; acc[i][j][1]=0.f; acc[i][j][2]=0.f; acc[i][j][3]=0.f; }

    for (int side = 0; side < 2; ++side) {
        if (side) __syncthreads();                   // all waves done reading LDS
        const unsigned short* Ap = side ? A2 : A1;
        const unsigned short* Wg = (side ? Wt2 : Wt1) + (size_t)g * 16384;
        #pragma unroll
        for (int p = 0; p < 8; ++p) {
            int id = t + 256 * p, r = id >> 4, c8 = id & 15;
            As[SWZ(r, c8)] = *(const uint4*)(Ap + (row0 + r) * GC + g * CH + c8 * 8);
        }
        #pragma unroll
        for (int p = 0; p < 8; ++p) {
            int id = t + 256 * p, r = id >> 4, c8 = id & 15;
            Bs[SWZ(r, c8)] = *(const uint4*)(Wg + r * CH + c8 * 8);
        }
        __syncthreads();
        #pragma unroll
        for (int kc = 0; kc < 4; ++kc) {
            int c8 = kc * 4 + q;
            bf16x8 a[4], b[4];
            #pragma unroll
            for (int i = 0; i < 4; ++i) { int r = m0 + i * 16 + lm; a[i] = *(const bf16x8*)&As[SWZ(r, c8)]; }
            #pragma unroll
            for (int j = 0; j < 4; ++j) { int r = n0 + j * 16 + lm; b[j] = *(const bf16x8*)&Bs[SWZ(r, c8)]; }
            #pragma unroll
            for (int i = 0; i < 4; ++i)
                #pragma unroll
                for (int j = 0; j < 4; ++j)
                    acc[i][j] = __builtin_amdgcn_mfma_f32_16x16x32_bf16(a[i], b[j], acc[i][j], 0, 0, 0);
        }
    }

    #pragma unroll
    for (int j = 0; j < 4; ++j)
        #pragma unroll
        for (int i = 0; i < 4; ++i)
            #pragma unroll
            for (int r = 0; r < 4; ++r) {
                int rowl = m0 + i * 16 + q * 4 + r;
                int col  = n0 + j * 16 + lm;
                float dr = dis[row0 + rowl];         // pre-scale for prop512g
                outS[(row0 + rowl) * GC + g * CH + col] = f2bf(dr * acc[i][j][r]);
            }
}

// ---------- 8. prop over 512-wide pre-scaled bf16 + FUSED LSTM gates ----------
// ONE NODE per 128-thread block: 2 waves each gather half the features (8B/lane),
// 8-edge unroll (uint2 keeps VGPR low -> occupancy stays high).
#define GIDX(f) ((f) + ((f) >> 5))                  // +1 float pad per 32 -> conflict-free
__global__ __launch_bounds__(128) void k_prop512g(
        const unsigned short* __restrict__ Sb, float* __restrict__ out,
        const int* __restrict__ rowoff, const int* __restrict__ csrs,
        const float* __restrict__ csrw, const float* __restrict__ dis,
        const float* __restrict__ c, const float* __restrict__ btot,
        const float* __restrict__ wc) {
    __shared__ float gbuf[528];                      // 2.1 KB
    int half = threadIdx.x >> 6, lane = threadIdx.x & 63;
    int w = blockIdx.x;                              // grid exact: NN blocks
    const uint2* S2 = (const uint2*)Sb;              // row = 128 uint2 = 1 KB
    size_t foff = (size_t)half * 64 + lane;          // uint2 offset within row
    float acc[4];
    tof4(S2[(size_t)w * 128 + foff], acc);           // self term (pre-scaled table)
    int e = rowoff[w], e1 = rowoff[w + 1];
    for (; e + 8 <= e1; e += 8) {                    // 8 gathers in flight
        int   s0 = csrs[e],   s1 = csrs[e+1], s2 = csrs[e+2], s3 = csrs[e+3];
        int   s4 = csrs[e+4], s5 = csrs[e+5], s6 = csrs[e+6], s7 = csrs[e+7];
        uint2 u0 = S2[(size_t)s0 * 128 + foff];
        uint2 u1 = S2[(size_t)s1 * 128 + foff];
        uint2 u2 = S2[(size_t)s2 * 128 + foff];
        uint2 u3 = S2[(size_t)s3 * 128 + foff];
        uint2 u4 = S2[(size_t)s4 * 128 + foff];
        uint2 u5 = S2[(size_t)s5 * 128 + foff];
        uint2 u6 = S2[(size_t)s6 * 128 + foff];
        uint2 u7 = S2[(size_t)s7 * 128 + foff];
        float n0 = csrw[e],   n1 = csrw[e+1], n2 = csrw[e+2], n3 = csrw[e+3];
        float n4 = csrw[e+4], n5 = csrw[e+5], n6 = csrw[e+6], n7 = csrw[e+7];
        fma4(u0, n0, acc); fma4(u1, n1, acc); fma4(u2, n2, acc); fma4(u3, n3, acc);
        fma4(u4, n4, acc); fma4(u5, n5, acc); fma4(u6, n6, acc); fma4(u7, n7, acc);
    }
    for (; e + 4 <= e1; e += 4) {
        int   s0 = csrs[e],   s1 = csrs[e+1], s2 = csrs[e+2], s3 = csrs[e+3];
        float n0 = csrw[e],   n1 = csrw[e+1], n2 = csrw[e+2], n3 = csrw[e+3];
        uint2 u0 = S2[(size_t)s0 * 128 + foff];
        uint2 u1 = S2[(size_t)s1 * 128 + foff];
        uint2 u2 = S2[(size_t)s2 * 128 + foff];
        uint2 u3 = S2[(size_t)s3 * 128 + foff];
        fma4(u0, n0, acc); fma4(u1, n1, acc); fma4(u2, n2, acc); fma4(u3, n3, acc);
    }
    for (; e < e1; ++e) {
        fma4(S2[(size_t)csrs[e] * 128 + foff], csrw[e], acc);
    }
    float dw = dis[w];
    #pragma unroll
    for (int j = 0; j < 4; ++j) {
        int f = half * 256 + lane * 4 + j;
        gbuf[GIDX(f)] = dw * acc[j];                 // G (pre-bias) into LDS
    }
    __syncthreads();
    int hh = threadIdx.x;                            // 0..127
    float g0 = gbuf[GIDX(hh)]       + btot[hh];
    float g1 = gbuf[GIDX(128 + hh)] + btot[128 + hh];
    float g2 = gbuf[GIDX(256 + hh)] + btot[256 + hh];
    float g3 = gbuf[GIDX(384 + hh)] + btot[384 + hh];
    float cv = c[(size_t)w * CH + hh];
    float I  = 1.f / (1.f + expf(-(g0 + wc[hh]       * cv)));
    float F  = 1.f / (1.f + expf(-(g1 + wc[128 + hh] * cv)));
    float T  = tanhf(g2);
    float Cn = F * cv + I * T;
    float O  = 1.f / (1.f + expf(-(g3 + wc[256 + hh] * Cn)));
    out[(size_t)w * CH + hh]         = O * tanhf(Cn);   // Hn
    out[NHtot + (size_t)w * CH + hh] = Cn;              // Cn
}

extern "C" void kernel_launch(void* const* d_in, const int* in_sizes, int n_in,
                              void* d_out, int out_size, void* d_ws, size_t ws_size,
                              hipStream_t stream) {
    (void)in_sizes; (void)n_in; (void)out_size; (void)ws_size;
    const float* x   = (const float*)d_in[0];
    const int*   ei  = (const int*)d_in[1];
    const float* ew  = (const float*)d_in[2];
    const float* h   = (const float*)d_in[3];
    const float* c   = (const float*)d_in[4];
    const float* Wx0 = (const float*)d_in[5];
    const float* bx0 = (const float*)d_in[6];
    const float* Wx1 = (const float*)d_in[7];
    const float* bx1 = (const float*)d_in[8];
    const float* Wh0 = (const float*)d_in[9];
    const float* bh0 = (const float*)d_in[10];
    const float* Wh1 = (const float*)d_in[11];
    const float* bh1 = (const float*)d_in[12];
    const float* wc  = (const float*)d_in[13];
    const float* bg  = (const float*)d_in[14];
    float* out = (float*)d_out;

    // Workspace layout (float units) — validated R7/R9/R10 layout.
    float* wsf  = (float*)d_ws;
    float* dis  = wsf;                                  // [20480]
    int*   cnt  = (int*)(wsf + 20480);                  // [20480]  zeroed
    int*   row  = (int*)(wsf + 40960);                  // [20736]
    int*   cur  = (int*)(wsf + 61696);                  // [20480]
    int*   bsum = (int*)(wsf + 82176);                  // [256]
    float* btot = wsf + 82432;                          // [512]
    int*   csrs = (int*)(wsf + 82944);                  // [E]
    float* csrw = wsf + 402944;                         // [E] raw weights
    unsigned short* Wt0x = (unsigned short*)(wsf + 722944);   // +32768 floats each
    unsigned short* Wt0h = (unsigned short*)(wsf + 755712);
    unsigned short* Wt1x = (unsigned short*)(wsf + 788480);
    unsigned short* Wt1h = (unsigned short*)(wsf + 821248);
    unsigned short* xhb  = (unsigned short*)(wsf + 854016);   // [NP*256] bf16
    unsigned short* axh  = (unsigned short*)(wsf + 3426304);  // [NP*256] bf16
    unsigned short* h0x  = (unsigned short*)(wsf + 5998592);  // [NP*512] bf16
    unsigned short* h0h  = (unsigned short*)(wsf + 11143168); // [NP*512] bf16
    unsigned short* Sb   = (unsigned short*)(wsf + 16287744); // [NP*512] bf16

    hipMemsetAsync(cnt, 0, 20480 * sizeof(int), stream);

    k_cntprep<<<EE / 256 + 1024, 256, 0, stream>>>(ei, cnt,
                                                   Wx0, Wh0, Wx1, Wh1,
                                                   Wt0x, Wt0h, Wt1x, Wt1h,
                                                   bx1, bh1, bg, btot);
    k_scan1  <<<80, 256, 0, stream>>>(cnt, row, bsum);
    k_scan2  <<<1, 64, 0, stream>>>(bsum);
    k_scan3  <<<80, 256, 0, stream>>>(row, bsum, cur);
    k_scatter<<<EE / 256, 256, 0, stream>>>(ei, ew, cur, csrs, csrw);

    k_degcast<<<NN / 4, 256, 0, stream>>>(x, h, row, csrw, dis, xhb);

    k_prop256<<<NN / 2, 128, 0, stream>>>(xhb, axh, row, csrs, csrw, dis);

    dim3 g1(NP / 128, 4, 2);
    k_gemm1<<<g1, 256, 0, stream>>>(axh, Wt0x, Wt0h, bx0, bh0, h0x, h0h);
    dim3 g2(NP / 128, 4);
    k_gemm2<<<g2, 256, 0, stream>>>(h0x, h0h, Wt1x, Wt1h, dis, Sb);

    k_prop512g<<<NN, 128, 0, stream>>>(Sb, out, row, csrs, csrw, dis, c, btot, wc);
}

// Round 13
// 249.932 us; speedup vs baseline: 1.1301x; 1.0129x over previous
//
#include <hip/hip_runtime.h>
#include <hip/hip_bf16.h>
#include <stdint.h>

// Problem constants (fixed by the reference)
#define NN    20000      // nodes
#define NP    20096      // nodes padded to 157*128 (garbage rows never read back)
#define EE    320000     // edges (w/o self loops)
#define CH    128        // feature width per gate
#define GC    512        // 4 gates * 128
#define NHtot 2560000    // N*CH

typedef short bf16x8 __attribute__((ext_vector_type(8)));   // 8 bf16 (4 VGPRs)
typedef float f32x4  __attribute__((ext_vector_type(4)));   // 4 fp32 acc

// ---------- bf16 helpers ----------
__device__ __forceinline__ unsigned short f2bf(float f) {
    __hip_bfloat16 b = __float2bfloat16(f);           // RNE
    union { __hip_bfloat16 b; unsigned short u; } c; c.b = b; return c.u;
}
// fast bf16x2 dword -> two f32: lo = u<<16, hi = u & 0xffff0000 (1 VALU op each)
__device__ __forceinline__ void fma4(uint2 u, float n, float* acc) {
    union { unsigned int i; float f; } t;
    t.i = u.x << 16;         acc[0] += n * t.f;
    t.i = u.x & 0xffff0000u; acc[1] += n * t.f;
    t.i = u.y << 16;         acc[2] += n * t.f;
    t.i = u.y & 0xffff0000u; acc[3] += n * t.f;
}
__device__ __forceinline__ void tof4(uint2 u, float* f) {
    union { unsigned int i; float f; } t;
    t.i = u.x << 16;         f[0] = t.f;
    t.i = u.x & 0xffff0000u; f[1] = t.f;
    t.i = u.y << 16;         f[2] = t.f;
    t.i = u.y & 0xffff0000u; f[3] = t.f;
}
__device__ __forceinline__ uint2 pack4(const float* f) {
    uint2 v;
    v.x = (unsigned int)f2bf(f[0]) | ((unsigned int)f2bf(f[1]) << 16);
    v.y = (unsigned int)f2bf(f[2]) | ((unsigned int)f2bf(f[3]) << 16);
    return v;
}
// async 16B global -> LDS (lane deposits at lds_base + lane*16)
__device__ __forceinline__ void gload_lds16(const void* g, void* l) {
    __builtin_amdgcn_global_load_lds(
        (const __attribute__((address_space(1))) void*)g,
        (__attribute__((address_space(3))) void*)l, 16, 0, 0);
}

// ---------- 1. MERGED: edge count (int atomics) + weight prep + btot ----------
// blocks [0,1250): count; blocks [1250,2274): transpose/cast weights (+btot).
__global__ void k_cntprep(const int* __restrict__ ei, int* __restrict__ cnt,
                          const float* __restrict__ W0, const float* __restrict__ W1,
                          const float* __restrict__ W2, const float* __restrict__ W3,
                          unsigned short* __restrict__ T0, unsigned short* __restrict__ T1,
                          unsigned short* __restrict__ T2, unsigned short* __restrict__ T3,
                          const float* __restrict__ bx1, const float* __restrict__ bh1,
                          const float* __restrict__ bg, float* __restrict__ btot) {
    int bid = blockIdx.x;
    if (bid < EE / 256) {
        int e = bid * 256 + threadIdx.x;
        atomicAdd(&cnt[ei[EE + e]], 1);
        return;
    }
    int pid = bid - EE / 256;                        // 0..1023
    int z = pid >> 8, y = (pid >> 6) & 3, xb = pid & 63;
    if (z == 0 && y == 0 && xb < 2) {
        int f = xb * 256 + threadIdx.x;              // 512 entries
        btot[f] = bx1[f] + bh1[f] + bg[f];
    }
    const float* W; unsigned short* T;
    switch (z) {
        case 0:  W = W0; T = T0; break;
        case 1:  W = W1; T = T1; break;
        case 2:  W = W2; T = T2; break;
        default: W = W3; T = T3; break;
    }
    int n = xb * 2 + (threadIdx.x >> 7);
    int k = threadIdx.x & 127;
    T[((size_t)y * 128 + n) * 128 + k] = f2bf(W[((size_t)y * 128 + k) * 128 + n]);
}

// ---------- 2. hierarchical exclusive scan of counts ----------
__global__ void k_scan1(const int* __restrict__ cnt, int* __restrict__ rowoff,
                        int* __restrict__ bsum) {
    __shared__ int wsum[4];
    int i = blockIdx.x * 256 + threadIdx.x;
    int self = (i < NN) ? cnt[i] : 0;
    int lane = threadIdx.x & 63, wid = threadIdx.x >> 6;
    int v = self;
    #pragma unroll
    for (int off = 1; off < 64; off <<= 1) {
        int u = __shfl_up(v, off);
        if (lane >= off) v += u;
    }
    if (lane == 63) wsum[wid] = v;
    __syncthreads();
    int wof = 0;
    for (int k = 0; k < wid; ++k) wof += wsum[k];
    if (i < NN) rowoff[i] = wof + v - self;
    if (threadIdx.x == 255) bsum[blockIdx.x] = wof + v;
}

__global__ void k_scan2(int* __restrict__ bsum) {
    int lane = threadIdx.x;                          // 64 threads
    int base = 0;
    for (int start = 0; start < 80; start += 64) {
        int i = start + lane;
        int self = (i < 80) ? bsum[i] : 0;
        int v = self;
        #pragma unroll
        for (int off = 1; off < 64; off <<= 1) {
            int u = __shfl_up(v, off);
            if (lane >= off) v += u;
        }
        if (i < 80) bsum[i] = base + v - self;
        base += __shfl(v, 63);
    }
}

__global__ void k_scan3(int* __restrict__ rowoff, const int* __restrict__ bsum,
                        int* __restrict__ cur) {
    int i = blockIdx.x * 256 + threadIdx.x;
    if (i < NN) {
        int v = rowoff[i] + bsum[i >> 8];
        rowoff[i] = v; cur[i] = v;
    }
    if (i == NN) rowoff[NN] = EE;
}

// ---------- 3. scatter edges into CSR with RAW weights ----------
__global__ void k_scatter(const int* __restrict__ ei, const float* __restrict__ ew,
                          int* __restrict__ cur,
                          int* __restrict__ csrs, float* __restrict__ csrw) {
    int e = blockIdx.x * 256 + threadIdx.x;
    if (e >= EE) return;
    int s = ei[e], d = ei[EE + e];
    int p = atomicAdd(&cur[d], 1);
    csrs[p] = s; csrw[p] = ew[e];
}

// ---------- 4. FUSED: degree row-sum -> dis -> scale & pack x|h to bf16 ----------
__global__ __launch_bounds__(256) void k_degcast(
        const float* __restrict__ x, const float* __restrict__ h,
        const int* __restrict__ rowoff, const float* __restrict__ csrw,
        float* __restrict__ dis, unsigned short* __restrict__ xhb) {
    int wid = threadIdx.x >> 6, lane = threadIdx.x & 63;
    int w = blockIdx.x * 4 + wid;                    // grid exact: NN/4
    int e0 = rowoff[w], e1 = rowoff[w + 1];
    float s = 0.f;
    for (int e = e0 + lane; e < e1; e += 64) s += csrw[e];
    #pragma unroll
    for (int off = 32; off; off >>= 1) s += __shfl_xor(s, off);
    float dn = rsqrtf(fmaxf(1.0f + s, 1e-12f));      // self-loop weight 1
    if (lane == 0) dis[w] = dn;
    const float* src = (lane < 32) ? x + (size_t)w * CH + lane * 4
                                   : h + (size_t)w * CH + (lane - 32) * 4;
    float4 v = *(const float4*)src;
    float f[4] = { dn * v.x, dn * v.y, dn * v.z, dn * v.w };
    *(uint2*)(xhb + (size_t)w * 256 + lane * 4) = pack4(f);
}

// ---------- 5. fused prop over packed 256-wide bf16 rows (table pre-scaled) ----------
// axh[w] = dis_w*(sum_e w_e*T[s_e] + T[w]); 1 wave/node, 8B/lane, 8-edge unroll.
__global__ __launch_bounds__(128) void k_prop256(
        const unsigned short* __restrict__ tab, unsigned short* __restrict__ o,
        const int* __restrict__ rowoff, const int* __restrict__ csrs,
        const float* __restrict__ csrw, const float* __restrict__ dis) {
    int w = blockIdx.x * 2 + (threadIdx.x >> 6);     // grid exact: NN/2 blocks
    int lane = threadIdx.x & 63;
    const uint2* T2 = (const uint2*)tab;             // row = 64 uint2 = 512 B
    float acc[4];
    tof4(T2[(size_t)w * 64 + lane], acc);            // self term (pre-scaled table)
    int e = rowoff[w], e1 = rowoff[w + 1];
    for (; e + 8 <= e1; e += 8) {                    // 8 gathers in flight
        int   s0 = csrs[e],   s1 = csrs[e+1], s2 = csrs[e+2], s3 = csrs[e+3];
        int   s4 = csrs[e+4], s5 = csrs[e+5], s6 = csrs[e+6], s7 = csrs[e+7];
        uint2 u0 = T2[(size_t)s0 * 64 + lane];
        uint2 u1 = T2[(size_t)s1 * 64 + lane];
        uint2 u2 = T2[(size_t)s2 * 64 + lane];
        uint2 u3 = T2[(size_t)s3 * 64 + lane];
        uint2 u4 = T2[(size_t)s4 * 64 + lane];
        uint2 u5 = T2[(size_t)s5 * 64 + lane];
        uint2 u6 = T2[(size_t)s6 * 64 + lane];
        uint2 u7 = T2[(size_t)s7 * 64 + lane];
        float n0 = csrw[e],   n1 = csrw[e+1], n2 = csrw[e+2], n3 = csrw[e+3];
        float n4 = csrw[e+4], n5 = csrw[e+5], n6 = csrw[e+6], n7 = csrw[e+7];
        fma4(u0, n0, acc); fma4(u1, n1, acc); fma4(u2, n2, acc); fma4(u3, n3, acc);
        fma4(u4, n4, acc); fma4(u5, n5, acc); fma4(u6, n6, acc); fma4(u7, n7, acc);
    }
    for (; e + 4 <= e1; e += 4) {
        int   s0 = csrs[e],   s1 = csrs[e+1], s2 = csrs[e+2], s3 = csrs[e+3];
        float n0 = csrw[e],   n1 = csrw[e+1], n2 = csrw[e+2], n3 = csrw[e+3];
        uint2 u0 = T2[(size_t)s0 * 64 + lane];
        uint2 u1 = T2[(size_t)s1 * 64 + lane];
        uint2 u2 = T2[(size_t)s2 * 64 + lane];
        uint2 u3 = T2[(size_t)s3 * 64 + lane];
        fma4(u0, n0, acc); fma4(u1, n1, acc); fma4(u2, n2, acc); fma4(u3, n3, acc);
    }
    for (; e < e1; ++e) {
        fma4(T2[(size_t)csrs[e] * 64 + lane], csrw[e], acc);
    }
    float dw = dis[w];
    #pragma unroll
    for (int j = 0; j < 4; ++j) acc[j] *= dw;
    ((uint2*)o)[(size_t)w * 64 + lane] = pack4(acc);
}

// ---------- MFMA GEMM shared machinery ----------
// LDS chunk id = r*16 + cc holds GLOBAL chunk (r, cc ^ (r&15)).  Staging via
// global_load_lds (lane-contiguous LDS) with the XOR applied on the GLOBAL
// index; fragment reads use SWZ as before -> zero bank conflicts.
#define SWZ(r, c8) (((r) << 4) + ((c8) ^ ((r) & 15)))

// ---------- 6. GEMM1 (both sides in one launch via blockIdx.z) ----------
// h0 = relu(axh[:, side] @ W0[g] + b0[g]) -> bf16 [NP,512]
__global__ __launch_bounds__(256) void k_gemm1(
        const unsigned short* __restrict__ A,
        const unsigned short* __restrict__ Wtx, const unsigned short* __restrict__ Wth,
        const float* __restrict__ bx0, const float* __restrict__ bh0,
        unsigned short* __restrict__ outx, unsigned short* __restrict__ outh) {
    __shared__ uint4 As[2048];                       // 32 KB
    __shared__ uint4 Bs[2048];                       // 32 KB
    const int side = blockIdx.z;
    const int aoff = side * 128;
    const unsigned short* Wt = side ? Wth : Wtx;
    const float* bias        = side ? bh0 : bx0;
    unsigned short* out      = side ? outh : outx;

    const int    g    = blockIdx.y;
    const size_t row0 = (size_t)blockIdx.x * 128;
    const int    t    = threadIdx.x;
    const int    wv   = t >> 6;                      // wave id (LDS base uniform)
    const unsigned short* Wg = Wt + (size_t)g * 16384;   // [n][k] bf16

    #pragma unroll
    for (int p = 0; p < 8; ++p) {                    // async stage A and W tiles
        int id = t + 256 * p, r = id >> 4, cc = id & 15;
        int c8 = cc ^ (r & 15);                      // XOR swizzle on global side
        gload_lds16(A + (row0 + r) * 256 + aoff + c8 * 8, &As[p * 256 + wv * 64]);
        gload_lds16(Wg + r * CH + c8 * 8,                 &Bs[p * 256 + wv * 64]);
    }
    __syncthreads();                                 // vmcnt(0) drain at barrier

    const int l = t & 63;
    const int m0 = (wv >> 1) * 64, n0 = (wv & 1) * 64;
    const int lm = l & 15, q = l >> 4;
    f32x4 acc[4][4];
    #pragma unroll
    for (int i = 0; i < 4; ++i)
        #pragma unroll
        for (int j = 0; j < 4; ++j) { acc[i][j][0]=0.f; acc[i][j][1]=0.f; acc[i][j][2]=0.f; acc[i][j][3]=0.f; }

    #pragma unroll
    for (int kc = 0; kc < 4; ++kc) {
        int c8 = kc * 4 + q;
        bf16x8 a[4], b[4];
        #pragma unroll
        for (int i = 0; i < 4; ++i) { int r = m0 + i * 16 + lm; a[i] = *(const bf16x8*)&As[SWZ(r, c8)]; }
        #pragma unroll
        for (int j = 0; j < 4; ++j) { int r = n0 + j * 16 + lm; b[j] = *(const bf16x8*)&Bs[SWZ(r, c8)]; }
        #pragma unroll
        for (int i = 0; i < 4; ++i)
            #pragma unroll
            for (int j = 0; j < 4; ++j)
                acc[i][j] = __builtin_amdgcn_mfma_f32_16x16x32_bf16(a[i], b[j], acc[i][j], 0, 0, 0);
    }

    #pragma unroll
    for (int j = 0; j < 4; ++j) {
        float bb = bias[g * CH + n0 + j * 16 + lm];
        #pragma unroll
        for (int i = 0; i < 4; ++i)
            #pragma unroll
            for (int r = 0; r < 4; ++r) {
                int rowl = m0 + i * 16 + q * 4 + r;   // C/D: row=(lane>>4)*4+reg
                int col  = n0 + j * 16 + lm;          //      col=lane&15
                out[(row0 + rowl) * GC + g * CH + col] = f2bf(fmaxf(acc[i][j][r] + bb, 0.f));
            }
    }
}

// ---------- 7. GEMM2 (fused): Sb = dis .* (h0x@Wx1 + h0h@Wh1) -> bf16 [NP,512] ----------
__global__ __launch_bounds__(256) void k_gemm2(
        const unsigned short* __restrict__ A1, const unsigned short* __restrict__ A2,
        const unsigned short* __restrict__ Wt1, const unsigned short* __restrict__ Wt2,
        const float* __restrict__ dis, unsigned short* __restrict__ outS) {
    __shared__ uint4 As[2048];
    __shared__ uint4 Bs[2048];
    const int    g    = blockIdx.y;
    const size_t row0 = (size_t)blockIdx.x * 128;
    const int    t    = threadIdx.x;
    const int    wv   = t >> 6;
    const int l = t & 63;
    const int m0 = (wv >> 1) * 64, n0 = (wv & 1) * 64;
    const int lm = l & 15, q = l >> 4;
    f32x4 acc[4][4];
    #pragma unroll
    for (int i = 0; i < 4; ++i)
        #pragma unroll
        for (int j = 0; j < 4; ++j) { acc[i][j][0]=0.f; acc[i][j][1]=0.f; acc[i][j][2]=0.f; acc[i][j][3]=0.f; }

    for (int side = 0; side < 2; ++side) {
        if (side) __syncthreads();                   // all waves done reading LDS
        const unsigned short* Ap = side ? A2 : A1;
        const unsigned short* Wg = (side ? Wt2 : Wt1) + (size_t)g * 16384;
        #pragma unroll
        for (int p = 0; p < 8; ++p) {                // async stage A and W tiles
            int id = t + 256 * p, r = id >> 4, cc = id & 15;
            int c8 = cc ^ (r & 15);
            gload_lds16(Ap + (row0 + r) * GC + g * CH + c8 * 8, &As[p * 256 + wv * 64]);
            gload_lds16(Wg + r * CH + c8 * 8,                   &Bs[p * 256 + wv * 64]);
        }
        __syncthreads();
        #pragma unroll
        for (int kc = 0; kc < 4; ++kc) {
            int c8 = kc * 4 + q;
            bf16x8 a[4], b[4];
            #pragma unroll
            for (int i = 0; i < 4; ++i) { int r = m0 + i * 16 + lm; a[i] = *(const bf16x8*)&As[SWZ(r, c8)]; }
            #pragma unroll
            for (int j = 0; j < 4; ++j) { int r = n0 + j * 16 + lm; b[j] = *(const bf16x8*)&Bs[SWZ(r, c8)]; }
            #pragma unroll
            for (int i = 0; i < 4; ++i)
                #pragma unroll
                for (int j = 0; j < 4; ++j)
                    acc[i][j] = __builtin_amdgcn_mfma_f32_16x16x32_bf16(a[i], b[j], acc[i][j], 0, 0, 0);
        }
    }

    #pragma unroll
    for (int j = 0; j < 4; ++j)
        #pragma unroll
        for (int i = 0; i < 4; ++i)
            #pragma unroll
            for (int r = 0; r < 4; ++r) {
                int rowl = m0 + i * 16 + q * 4 + r;
                int col  = n0 + j * 16 + lm;
                float dr = dis[row0 + rowl];         // pre-scale for prop512g
                outS[(row0 + rowl) * GC + g * CH + col] = f2bf(dr * acc[i][j][r]);
            }
}

// ---------- 8. prop over 512-wide pre-scaled bf16 + FUSED LSTM gates ----------
// ONE NODE per 128-thread block: 2 waves each gather half the features (8B/lane),
// 8-edge unroll (uint2 keeps VGPR low -> occupancy stays high).
#define GIDX(f) ((f) + ((f) >> 5))                  // +1 float pad per 32 -> conflict-free
__global__ __launch_bounds__(128) void k_prop512g(
        const unsigned short* __restrict__ Sb, float* __restrict__ out,
        const int* __restrict__ rowoff, const int* __restrict__ csrs,
        const float* __restrict__ csrw, const float* __restrict__ dis,
        const float* __restrict__ c, const float* __restrict__ btot,
        const float* __restrict__ wc) {
    __shared__ float gbuf[528];                      // 2.1 KB
    int half = threadIdx.x >> 6, lane = threadIdx.x & 63;
    int w = blockIdx.x;                              // grid exact: NN blocks
    const uint2* S2 = (const uint2*)Sb;              // row = 128 uint2 = 1 KB
    size_t foff = (size_t)half * 64 + lane;          // uint2 offset within row
    float acc[4];
    tof4(S2[(size_t)w * 128 + foff], acc);           // self term (pre-scaled table)
    int e = rowoff[w], e1 = rowoff[w + 1];
    for (; e + 8 <= e1; e += 8) {                    // 8 gathers in flight
        int   s0 = csrs[e],   s1 = csrs[e+1], s2 = csrs[e+2], s3 = csrs[e+3];
        int   s4 = csrs[e+4], s5 = csrs[e+5], s6 = csrs[e+6], s7 = csrs[e+7];
        uint2 u0 = S2[(size_t)s0 * 128 + foff];
        uint2 u1 = S2[(size_t)s1 * 128 + foff];
        uint2 u2 = S2[(size_t)s2 * 128 + foff];
        uint2 u3 = S2[(size_t)s3 * 128 + foff];
        uint2 u4 = S2[(size_t)s4 * 128 + foff];
        uint2 u5 = S2[(size_t)s5 * 128 + foff];
        uint2 u6 = S2[(size_t)s6 * 128 + foff];
        uint2 u7 = S2[(size_t)s7 * 128 + foff];
        float n0 = csrw[e],   n1 = csrw[e+1], n2 = csrw[e+2], n3 = csrw[e+3];
        float n4 = csrw[e+4], n5 = csrw[e+5], n6 = csrw[e+6], n7 = csrw[e+7];
        fma4(u0, n0, acc); fma4(u1, n1, acc); fma4(u2, n2, acc); fma4(u3, n3, acc);
        fma4(u4, n4, acc); fma4(u5, n5, acc); fma4(u6, n6, acc); fma4(u7, n7, acc);
    }
    for (; e + 4 <= e1; e += 4) {
        int   s0 = csrs[e],   s1 = csrs[e+1], s2 = csrs[e+2], s3 = csrs[e+3];
        float n0 = csrw[e],   n1 = csrw[e+1], n2 = csrw[e+2], n3 = csrw[e+3];
        uint2 u0 = S2[(size_t)s0 * 128 + foff];
        uint2 u1 = S2[(size_t)s1 * 128 + foff];
        uint2 u2 = S2[(size_t)s2 * 128 + foff];
        uint2 u3 = S2[(size_t)s3 * 128 + foff];
        fma4(u0, n0, acc); fma4(u1, n1, acc); fma4(u2, n2, acc); fma4(u3, n3, acc);
    }
    for (; e < e1; ++e) {
        fma4(S2[(size_t)csrs[e] * 128 + foff], csrw[e], acc);
    }
    float dw = dis[w];
    #pragma unroll
    for (int j = 0; j < 4; ++j) {
        int f = half * 256 + lane * 4 + j;
        gbuf[GIDX(f)] = dw * acc[j];                 // G (pre-bias) into LDS
    }
    __syncthreads();
    int hh = threadIdx.x;                            // 0..127
    float g0 = gbuf[GIDX(hh)]       + btot[hh];
    float g1 = gbuf[GIDX(128 + hh)] + btot[128 + hh];
    float g2 = gbuf[GIDX(256 + hh)] + btot[256 + hh];
    float g3 = gbuf[GIDX(384 + hh)] + btot[384 + hh];
    float cv = c[(size_t)w * CH + hh];
    float I  = 1.f / (1.f + expf(-(g0 + wc[hh]       * cv)));
    float F  = 1.f / (1.f + expf(-(g1 + wc[128 + hh] * cv)));
    float T  = tanhf(g2);
    float Cn = F * cv + I * T;
    float O  = 1.f / (1.f + expf(-(g3 + wc[256 + hh] * Cn)));
    out[(size_t)w * CH + hh]         = O * tanhf(Cn);   // Hn
    out[NHtot + (size_t)w * CH + hh] = Cn;              // Cn
}

extern "C" void kernel_launch(void* const* d_in, const int* in_sizes, int n_in,
                              void* d_out, int out_size, void* d_ws, size_t ws_size,
                              hipStream_t stream) {
    (void)in_sizes; (void)n_in; (void)out_size; (void)ws_size;
    const float* x   = (const float*)d_in[0];
    const int*   ei  = (const int*)d_in[1];
    const float* ew  = (const float*)d_in[2];
    const float* h   = (const float*)d_in[3];
    const float* c   = (const float*)d_in[4];
    const float* Wx0 = (const float*)d_in[5];
    const float* bx0 = (const float*)d_in[6];
    const float* Wx1 = (const float*)d_in[7];
    const float* bx1 = (const float*)d_in[8];
    const float* Wh0 = (const float*)d_in[9];
    const float* bh0 = (const float*)d_in[10];
    const float* Wh1 = (const float*)d_in[11];
    const float* bh1 = (const float*)d_in[12];
    const float* wc  = (const float*)d_in[13];
    const float* bg  = (const float*)d_in[14];
    float* out = (float*)d_out;

    // Workspace layout (float units) — validated R7/R9/R10/R12 layout.
    float* wsf  = (float*)d_ws;
    float* dis  = wsf;                                  // [20480]
    int*   cnt  = (int*)(wsf + 20480);                  // [20480]  zeroed
    int*   row  = (int*)(wsf + 40960);                  // [20736]
    int*   cur  = (int*)(wsf + 61696);                  // [20480]
    int*   bsum = (int*)(wsf + 82176);                  // [256]
    float* btot = wsf + 82432;                          // [512]
    int*   csrs = (int*)(wsf + 82944);                  // [E]
    float* csrw = wsf + 402944;                         // [E] raw weights
    unsigned short* Wt0x = (unsigned short*)(wsf + 722944);   // +32768 floats each
    unsigned short* Wt0h = (unsigned short*)(wsf + 755712);
    unsigned short* Wt1x = (unsigned short*)(wsf + 788480);
    unsigned short* Wt1h = (unsigned short*)(wsf + 821248);
    unsigned short* xhb  = (unsigned short*)(wsf + 854016);   // [NP*256] bf16
    unsigned short* axh  = (unsigned short*)(wsf + 3426304);  // [NP*256] bf16
    unsigned short* h0x  = (unsigned short*)(wsf + 5998592);  // [NP*512] bf16
    unsigned short* h0h  = (unsigned short*)(wsf + 11143168); // [NP*512] bf16
    unsigned short* Sb   = (unsigned short*)(wsf + 16287744); // [NP*512] bf16

    hipMemsetAsync(cnt, 0, 20480 * sizeof(int), stream);

    k_cntprep<<<EE / 256 + 1024, 256, 0, stream>>>(ei, cnt,
                                                   Wx0, Wh0, Wx1, Wh1,
                                                   Wt0x, Wt0h, Wt1x, Wt1h,
                                                   bx1, bh1, bg, btot);
    k_scan1  <<<80, 256, 0, stream>>>(cnt, row, bsum);
    k_scan2  <<<1, 64, 0, stream>>>(bsum);
    k_scan3  <<<80, 256, 0, stream>>>(row, bsum, cur);
    k_scatter<<<EE / 256, 256, 0, stream>>>(ei, ew, cur, csrs, csrw);

    k_degcast<<<NN / 4, 256, 0, stream>>>(x, h, row, csrw, dis, xhb);

    k_prop256<<<NN / 2, 128, 0, stream>>>(xhb, axh, row, csrs, csrw, dis);

    dim3 g1(NP / 128, 4, 2);
    k_gemm1<<<g1, 256, 0, stream>>>(axh, Wt0x, Wt0h, bx0, bh0, h0x, h0h);
    dim3 g2(NP / 128, 4);
    k_gemm2<<<g2, 256, 0, stream>>>(h0x, h0h, Wt1x, Wt1h, dis, Sb);

    k_prop512g<<<NN, 128, 0, stream>>>(Sb, out, row, csrs, csrw, dis, c, btot, wc);
}